// Round 6
// baseline (291.259 us; speedup 1.0000x reference)
//
#include <hip/hip_runtime.h>
#include <hip/hip_bf16.h>

#define NPANEL 16   /* columns per panel */

// ---------------- CSR build ----------------

__global__ void k_count_deg(const int* __restrict__ dst, int* __restrict__ deg, int e) {
    int i = blockIdx.x * blockDim.x + threadIdx.x;
    int stride = gridDim.x * blockDim.x;
    for (; i < e; i += stride) atomicAdd(&deg[dst[i]], 1);
}

// pass 1: per-block (512 elems) sums + dinv
__global__ __launch_bounds__(512) void k_scan1(const int* __restrict__ deg,
                                               float* __restrict__ dinv,
                                               int* __restrict__ bsum, int n) {
    int t = threadIdx.x;
    int i = blockIdx.x * 512 + t;
    int d = (i < n) ? deg[i] : 0;
    if (i < n) dinv[i] = rsqrtf((float)(d + 1));   // +1 self-loop
    int v = d;
#pragma unroll
    for (int off = 32; off > 0; off >>= 1) v += __shfl_xor(v, off, 64);
    __shared__ int wsum[8];
    if ((t & 63) == 0) wsum[t >> 6] = v;
    __syncthreads();
    if (t == 0) {
        int s = 0;
#pragma unroll
        for (int j = 0; j < 8; ++j) s += wsum[j];
        bsum[blockIdx.x] = s;
    }
}

// pass 2 (merged): block offset computed in-block from bsum, then local scan -> rowptr
__global__ __launch_bounds__(512) void k_scan3(const int* __restrict__ deg,
                                               const int* __restrict__ bsum,
                                               int* __restrict__ rowptr, int n) {
    __shared__ int sm[512];
    __shared__ int sboff;
    int t = threadIdx.x;
    // block offset = sum of bsum[0 .. blockIdx.x)
    int v = (t < blockIdx.x) ? bsum[t] : 0;
#pragma unroll
    for (int off = 32; off > 0; off >>= 1) v += __shfl_xor(v, off, 64);
    if ((t & 63) == 0) sm[t >> 6] = v;
    __syncthreads();
    if (t == 0) {
        int s = 0;
#pragma unroll
        for (int j = 0; j < 8; ++j) s += sm[j];
        sboff = s;
    }
    __syncthreads();
    int boff = sboff;
    __syncthreads();                     // sm reuse barrier
    int i = blockIdx.x * 512 + t;
    int d = (i < n) ? deg[i] : 0;
    sm[t] = d;
    __syncthreads();
    for (int dd = 1; dd < 512; dd <<= 1) {
        int vv = (t >= dd) ? sm[t - dd] : 0;
        __syncthreads();
        sm[t] += vv;
        __syncthreads();
    }
    int excl = sm[t] - d;
    if (i < n) {
        rowptr[i] = boff + excl;
        if (i == n - 1) rowptr[n] = boff + excl + d;
    }
}

__global__ void k_scatter(const int* __restrict__ src, const int* __restrict__ dst,
                          const int* __restrict__ rowptr, int* __restrict__ cursor,
                          int* __restrict__ eidx, int e) {
    int i = blockIdx.x * blockDim.x + threadIdx.x;
    int stride = gridDim.x * blockDim.x;
    for (; i < e; i += stride) {
        int d = dst[i];
        int pos = rowptr[d] + atomicAdd(&cursor[d], 1);
        eidx[pos] = src[i];
    }
}

// ---------------- layer 1 GEMM: h1p[p][N][16] = x @ W1 (panel-major out) ----------------

#define GR 64

__global__ __launch_bounds__(512) void k_gemm1(const float* __restrict__ x,
                                               const float* __restrict__ W,
                                               float* __restrict__ h1p, int n) {
    __shared__ float Wl[128 * 128];   // 64 KB, [k][c]
    int t = threadIdx.x;

    const float4* Wg = (const float4*)W;
    float4* Wl4 = (float4*)Wl;
#pragma unroll
    for (int ii = 0; ii < 8; ++ii) Wl4[t + 512 * ii] = Wg[t + 512 * ii];
    __syncthreads();

    long long row0 = (long long)blockIdx.x * GR;
    int rows = (int)(((long long)n - row0 < GR) ? ((long long)n - row0) : GR);

    int tx = t & 31, ty = t >> 5;
    int c0 = tx * 4, r0 = ty * 4;

    const float4* xr[4];
#pragma unroll
    for (int q = 0; q < 4; ++q) {
        int r = r0 + q; if (r >= rows) r = 0;
        xr[q] = (const float4*)(x + (row0 + r) * 128);
    }

    float acc[4][4];
#pragma unroll
    for (int q = 0; q < 4; ++q)
#pragma unroll
        for (int j = 0; j < 4; ++j) acc[q][j] = 0.f;

#pragma unroll 4
    for (int kc = 0; kc < 32; ++kc) {
        float4 xv[4];
#pragma unroll
        for (int q = 0; q < 4; ++q) xv[q] = xr[q][kc];
#pragma unroll
        for (int kk = 0; kk < 4; ++kk) {
            float4 wv = *(const float4*)&Wl[(kc * 4 + kk) * 128 + c0];
#pragma unroll
            for (int q = 0; q < 4; ++q) {
                float xq = ((const float*)&xv[q])[kk];
                acc[q][0] += xq * wv.x;
                acc[q][1] += xq * wv.y;
                acc[q][2] += xq * wv.z;
                acc[q][3] += xq * wv.w;
            }
        }
    }

    // panel-major store: panel = c0>>4, within-panel col = c0&15 (16B-aligned float4)
    float* hp = h1p + (size_t)(c0 >> 4) * n * NPANEL + (c0 & 15);
#pragma unroll
    for (int q = 0; q < 4; ++q) {
        if (r0 + q < rows) {
            float4 o = make_float4(acc[q][0], acc[q][1], acc[q][2], acc[q][3]);
            *(float4*)&hp[(size_t)(row0 + r0 + q) * NPANEL] = o;
        }
    }
}

// ---------------- layer-1 aggregation, XCD-panel-sharded ----------------
// panel = blockIdx.x & 7 -> one 3.2MB h1 panel per XCD (L2-resident).
// 64-lane wave = 4 nodes x 16 lanes; 64B gathers per edge-visit.

__global__ __launch_bounds__(256) void k_aggp(
    const int* __restrict__ rowptr, const int* __restrict__ eidx,
    const float* __restrict__ dinv, const float* __restrict__ h1p,
    float* __restrict__ aggp, int n) {
    int p  = blockIdx.x & 7;
    int vb = blockIdx.x >> 3;
    int nvb = gridDim.x >> 3;
    const float* hp = h1p + (size_t)p * n * NPANEL;
    float* ap = aggp + (size_t)p * n * NPANEL;
    int lane = threadIdx.x & 63;
    int g = lane >> 4;         // node-group 0..3
    int c = lane & 15;         // column within panel
    int wid = threadIdx.x >> 6;
    int base = (vb * (blockDim.x >> 6) + wid) * 4 + g;
    int stride = nvb * (blockDim.x >> 6) * 4;
    for (int i = base; i < n; i += stride) {
        float di = dinv[i];
        float acc = di * di * hp[(size_t)i * NPANEL + c];
        int j = rowptr[i], end = rowptr[i + 1];
        for (; j + 4 <= end; j += 4) {
            int s0 = eidx[j], s1 = eidx[j + 1], s2 = eidx[j + 2], s3 = eidx[j + 3];
            float n0 = dinv[s0] * di, n1 = dinv[s1] * di;
            float n2 = dinv[s2] * di, n3 = dinv[s3] * di;
            float v0 = hp[(size_t)s0 * NPANEL + c];
            float v1 = hp[(size_t)s1 * NPANEL + c];
            float v2 = hp[(size_t)s2 * NPANEL + c];
            float v3 = hp[(size_t)s3 * NPANEL + c];
            acc += v0 * n0 + v1 * n1 + v2 * n2 + v3 * n3;
        }
        for (; j < end; ++j) {
            int ss = eidx[j];
            acc += hp[(size_t)ss * NPANEL + c] * (dinv[ss] * di);
        }
        ap[(size_t)i * NPANEL + c] = acc;
    }
}

// ---------------- s = relu(agg + b1) @ W2 ----------------
// wave per node; lane l covers global cols 2l,2l+1 (panel-major layout).

__global__ __launch_bounds__(256) void k_sdot(
    const float* __restrict__ aggp, const float* __restrict__ b1,
    const float* __restrict__ W2, float* __restrict__ s, int n) {
    int lane = threadIdx.x & 63;
    int wid = blockIdx.x * (blockDim.x >> 6) + (threadIdx.x >> 6);
    int nw = gridDim.x * (blockDim.x >> 6);
    float2 bb = ((const float2*)b1)[lane];
    float2 ww = ((const float2*)W2)[lane];
    int p = lane >> 3;
    int c = (lane & 7) * 2;
    for (int i = wid; i < n; i += nw) {
        float2 v = *(const float2*)(aggp + ((size_t)p * n + i) * NPANEL + c);
        float acc = fmaxf(v.x + bb.x, 0.f) * ww.x + fmaxf(v.y + bb.y, 0.f) * ww.y;
#pragma unroll
        for (int off = 32; off > 0; off >>= 1) acc += __shfl_xor(acc, off, 64);
        if (lane == 0) s[i] = acc;
    }
}

// ---------------- layer 2: per-thread CSR gather of s ----------------

__global__ void k_out2(const int* __restrict__ rowptr, const int* __restrict__ eidx,
                       const float* __restrict__ dinv, const float* __restrict__ s,
                       const float* __restrict__ b2, float* __restrict__ out, int n) {
    int i = blockIdx.x * blockDim.x + threadIdx.x;
    if (i >= n) return;
    float di = dinv[i];
    float acc = di * s[i];
    int j = rowptr[i], end = rowptr[i + 1];
    for (; j < end; ++j) {
        int ss = eidx[j];
        acc += dinv[ss] * s[ss];
    }
    out[i] = b2[0] + di * acc;
}

// ---------------- launch ----------------

extern "C" void kernel_launch(void* const* d_in, const int* in_sizes, int n_in,
                              void* d_out, int out_size, void* d_ws, size_t ws_size,
                              hipStream_t stream) {
    const float* x  = (const float*)d_in[0];
    const int*   ei = (const int*)d_in[1];   // [2,E] int32
    const float* W1 = (const float*)d_in[2];
    const float* b1 = (const float*)d_in[3];
    const float* W2 = (const float*)d_in[4];
    const float* b2 = (const float*)d_in[5];
    float* out = (float*)d_out;

    int n = in_sizes[0] / 128;
    int e = in_sizes[1] / 2;
    const int* srcp = ei;
    const int* dstp = ei + e;

    char* ws = (char*)d_ws;
    size_t off = 0;
    auto take = [&](size_t bytes) -> char* {
        char* p = ws + off;
        off += (bytes + 255) & ~(size_t)255;
        return p;
    };
    int*   deg    = (int*)take((size_t)n * 4);
    int*   cursor = (int*)take((size_t)n * 4);   // adjacent to deg (joint memset)
    int*   rowptr = (int*)take((size_t)(n + 1) * 4);
    float* dinv   = (float*)take((size_t)n * 4);
    float* s      = (float*)take((size_t)n * 4);
    int*   eidx   = (int*)take((size_t)e * 4);
    int*   bsum   = (int*)take((size_t)512 * 4);
    float* h1p    = (float*)take((size_t)n * 128 * 4);
    float* aggp   = (float*)take((size_t)n * 128 * 4);
    (void)ws_size;

    int egrid = (e + 255) / 256; if (egrid > 2048) egrid = 2048;
    int ngrid = (n + 255) / 256;
    int nscan = (n + 511) / 512;   // 98 blocks (must be <= 512)

    hipMemsetAsync(deg, 0, (((size_t)n * 4 + 255) & ~(size_t)255) + (size_t)n * 4, stream);

    hipLaunchKernelGGL(k_count_deg, dim3(egrid), dim3(256), 0, stream, dstp, deg, e);
    hipLaunchKernelGGL(k_scan1, dim3(nscan), dim3(512), 0, stream, deg, dinv, bsum, n);
    hipLaunchKernelGGL(k_scan3, dim3(nscan), dim3(512), 0, stream, deg, bsum, rowptr, n);
    hipLaunchKernelGGL(k_scatter, dim3(egrid), dim3(256), 0, stream,
                       srcp, dstp, rowptr, cursor, eidx, e);
    hipLaunchKernelGGL(k_gemm1, dim3((n + GR - 1) / GR), dim3(512), 0, stream,
                       x, W1, h1p, n);
    hipLaunchKernelGGL(k_aggp, dim3(2048), dim3(256), 0, stream,
                       rowptr, eidx, dinv, h1p, aggp, n);
    hipLaunchKernelGGL(k_sdot, dim3(2048), dim3(256), 0, stream,
                       aggp, b1, W2, s, n);
    hipLaunchKernelGGL(k_out2, dim3(ngrid), dim3(256), 0, stream,
                       rowptr, eidx, dinv, s, b2, out, n);
}

// Round 10
// 240.032 us; speedup vs baseline: 1.2134x; 1.2134x over previous
//
#include <hip/hip_runtime.h>
#include <hip/hip_fp16.h>

// ---------------- CSR build ----------------

__global__ void k_count_deg(const int* __restrict__ dst, int* __restrict__ deg, int e) {
    int i = blockIdx.x * blockDim.x + threadIdx.x;
    int stride = gridDim.x * blockDim.x;
    for (; i < e; i += stride) atomicAdd(&deg[dst[i]], 1);
}

// pass 1: per-block (512 elems) sums + dinv = rsqrt(deg+1)
__global__ __launch_bounds__(512) void k_scan1(const int* __restrict__ deg,
                                               float* __restrict__ dinv,
                                               int* __restrict__ bsum, int n) {
    int t = threadIdx.x;
    int i = blockIdx.x * 512 + t;
    int d = (i < n) ? deg[i] : 0;
    if (i < n) dinv[i] = rsqrtf((float)(d + 1));   // +1 self-loop
    int v = d;
#pragma unroll
    for (int off = 32; off > 0; off >>= 1) v += __shfl_xor(v, off, 64);
    __shared__ int wsum[8];
    if ((t & 63) == 0) wsum[t >> 6] = v;
    __syncthreads();
    if (t == 0) {
        int s = 0;
#pragma unroll
        for (int j = 0; j < 8; ++j) s += wsum[j];
        bsum[blockIdx.x] = s;
    }
}

// pass 2 (merged): block offset from bsum in-block, then local scan -> rowptr
__global__ __launch_bounds__(512) void k_scan3(const int* __restrict__ deg,
                                               const int* __restrict__ bsum,
                                               int* __restrict__ rowptr, int n) {
    __shared__ int sm[512];
    __shared__ int sboff;
    int t = threadIdx.x;
    int v = (t < blockIdx.x) ? bsum[t] : 0;
#pragma unroll
    for (int off = 32; off > 0; off >>= 1) v += __shfl_xor(v, off, 64);
    if ((t & 63) == 0) sm[t >> 6] = v;
    __syncthreads();
    if (t == 0) {
        int s = 0;
#pragma unroll
        for (int j = 0; j < 8; ++j) s += sm[j];
        sboff = s;
    }
    __syncthreads();
    int boff = sboff;
    __syncthreads();                     // sm reuse barrier
    int i = blockIdx.x * 512 + t;
    int d = (i < n) ? deg[i] : 0;
    sm[t] = d;
    __syncthreads();
    for (int dd = 1; dd < 512; dd <<= 1) {
        int vv = (t >= dd) ? sm[t - dd] : 0;
        __syncthreads();
        sm[t] += vv;
        __syncthreads();
    }
    int excl = sm[t] - d;
    if (i < n) {
        rowptr[i] = boff + excl;
        if (i == n - 1) rowptr[n] = boff + excl + d;
    }
}

// scatter-fill packed edge records {src, norm=dinv[src]*dinv[dst]}
__global__ void k_scatter(const int* __restrict__ src, const int* __restrict__ dst,
                          const int* __restrict__ rowptr, int* __restrict__ cursor,
                          const float* __restrict__ dinv,
                          int2* __restrict__ enorm, int e) {
    int i = blockIdx.x * blockDim.x + threadIdx.x;
    int stride = gridDim.x * blockDim.x;
    for (; i < e; i += stride) {
        int ss = src[i];
        int dd = dst[i];
        int pos = rowptr[dd] + atomicAdd(&cursor[dd], 1);
        float nn = dinv[ss] * dinv[dd];
        enorm[pos] = make_int2(ss, __float_as_int(nn));
    }
}

// ---------------- layer 1 GEMM: h1 (fp16) = x @ W1 ----------------

#define GR 64

__global__ __launch_bounds__(512) void k_gemm1(const float* __restrict__ x,
                                               const float* __restrict__ W,
                                               __half* __restrict__ h1, int n) {
    __shared__ float Wl[128 * 128];   // 64 KB, [k][c]
    int t = threadIdx.x;

    const float4* Wg = (const float4*)W;
    float4* Wl4 = (float4*)Wl;
#pragma unroll
    for (int ii = 0; ii < 8; ++ii) Wl4[t + 512 * ii] = Wg[t + 512 * ii];
    __syncthreads();

    long long row0 = (long long)blockIdx.x * GR;
    int rows = (int)(((long long)n - row0 < GR) ? ((long long)n - row0) : GR);

    int tx = t & 31, ty = t >> 5;
    int c0 = tx * 4, r0 = ty * 4;

    const float4* xr[4];
#pragma unroll
    for (int q = 0; q < 4; ++q) {
        int r = r0 + q; if (r >= rows) r = 0;
        xr[q] = (const float4*)(x + (row0 + r) * 128);
    }

    float acc[4][4];
#pragma unroll
    for (int q = 0; q < 4; ++q)
#pragma unroll
        for (int j = 0; j < 4; ++j) acc[q][j] = 0.f;

#pragma unroll 4
    for (int kc = 0; kc < 32; ++kc) {
        float4 xv[4];
#pragma unroll
        for (int q = 0; q < 4; ++q) xv[q] = xr[q][kc];
#pragma unroll
        for (int kk = 0; kk < 4; ++kk) {
            float4 wv = *(const float4*)&Wl[(kc * 4 + kk) * 128 + c0];
#pragma unroll
            for (int q = 0; q < 4; ++q) {
                float xq = ((const float*)&xv[q])[kk];
                acc[q][0] += xq * wv.x;
                acc[q][1] += xq * wv.y;
                acc[q][2] += xq * wv.z;
                acc[q][3] += xq * wv.w;
            }
        }
    }

#pragma unroll
    for (int q = 0; q < 4; ++q) {
        if (r0 + q < rows) {
            ushort4 o;
            o.x = __half_as_ushort(__float2half(acc[q][0]));
            o.y = __half_as_ushort(__float2half(acc[q][1]));
            o.z = __half_as_ushort(__float2half(acc[q][2]));
            o.w = __half_as_ushort(__float2half(acc[q][3]));
            *(ushort4*)&h1[(size_t)(row0 + r0 + q) * 128 + c0] = o;
        }
    }
}

// ---------------- fused layer-1 agg + bias + relu + W2 dot ----------------
// one wave per node; lane covers cols 2l,2l+1 (half2 = 4B gather per lane).

__global__ __launch_bounds__(256) void k_agg_s(
    const int* __restrict__ rowptr, const int2* __restrict__ enorm,
    const float* __restrict__ dinv, const __half* __restrict__ h1,
    const float* __restrict__ b1, const float* __restrict__ W2,
    float* __restrict__ s, int n) {
    int lane = threadIdx.x & 63;
    int wid = blockIdx.x * (blockDim.x >> 6) + (threadIdx.x >> 6);
    wid = __builtin_amdgcn_readfirstlane(wid);
    int nw = gridDim.x * (blockDim.x >> 6);
    float2 bb = ((const float2*)b1)[lane];
    float2 ww = ((const float2*)W2)[lane];
    for (int i = wid; i < n; i += nw) {
        float di = dinv[i];
        float2 acc = __half22float2(((const __half2*)(h1 + (size_t)i * 128))[lane]);
        float self = di * di;
        acc.x *= self; acc.y *= self;
        int j = rowptr[i], end = rowptr[i + 1];
        for (; j + 4 <= end; j += 4) {
            int2 e0 = enorm[j],     e1 = enorm[j + 1];
            int2 e2 = enorm[j + 2], e3 = enorm[j + 3];
            float n0 = __int_as_float(e0.y), n1 = __int_as_float(e1.y);
            float n2 = __int_as_float(e2.y), n3 = __int_as_float(e3.y);
            float2 v0 = __half22float2(((const __half2*)(h1 + (size_t)e0.x * 128))[lane]);
            float2 v1 = __half22float2(((const __half2*)(h1 + (size_t)e1.x * 128))[lane]);
            float2 v2 = __half22float2(((const __half2*)(h1 + (size_t)e2.x * 128))[lane]);
            float2 v3 = __half22float2(((const __half2*)(h1 + (size_t)e3.x * 128))[lane]);
            acc.x += v0.x * n0; acc.y += v0.y * n0;
            acc.x += v1.x * n1; acc.y += v1.y * n1;
            acc.x += v2.x * n2; acc.y += v2.y * n2;
            acc.x += v3.x * n3; acc.y += v3.y * n3;
        }
        for (; j < end; ++j) {
            int2 e0 = enorm[j];
            float nn = __int_as_float(e0.y);
            float2 v = __half22float2(((const __half2*)(h1 + (size_t)e0.x * 128))[lane]);
            acc.x += v.x * nn; acc.y += v.y * nn;
        }
        float p = fmaxf(acc.x + bb.x, 0.f) * ww.x + fmaxf(acc.y + bb.y, 0.f) * ww.y;
#pragma unroll
        for (int off = 32; off > 0; off >>= 1)
            p += __shfl_xor(p, off, 64);
        if (lane == 0) s[i] = p;
    }
}

// ---------------- layer 2: per-thread CSR gather of s via packed records ----------------

__global__ void k_out2(const int* __restrict__ rowptr, const int2* __restrict__ enorm,
                       const float* __restrict__ dinv, const float* __restrict__ s,
                       const float* __restrict__ b2, float* __restrict__ out, int n) {
    int i = blockIdx.x * blockDim.x + threadIdx.x;
    if (i >= n) return;
    float di = dinv[i];
    float acc = di * di * s[i];            // self-loop
    int j = rowptr[i], end = rowptr[i + 1];
    for (; j < end; ++j) {
        int2 e0 = enorm[j];
        acc += __int_as_float(e0.y) * s[e0.x];
    }
    out[i] = b2[0] + acc;
}

// ---------------- launch ----------------

extern "C" void kernel_launch(void* const* d_in, const int* in_sizes, int n_in,
                              void* d_out, int out_size, void* d_ws, size_t ws_size,
                              hipStream_t stream) {
    const float* x  = (const float*)d_in[0];
    const int*   ei = (const int*)d_in[1];   // [2,E] int32
    const float* W1 = (const float*)d_in[2];
    const float* b1 = (const float*)d_in[3];
    const float* W2 = (const float*)d_in[4];
    const float* b2 = (const float*)d_in[5];
    float* out = (float*)d_out;

    int n = in_sizes[0] / 128;
    int e = in_sizes[1] / 2;
    const int* srcp = ei;
    const int* dstp = ei + e;

    char* ws = (char*)d_ws;
    size_t off = 0;
    auto take = [&](size_t bytes) -> char* {
        char* p = ws + off;
        off += (bytes + 255) & ~(size_t)255;
        return p;
    };
    int*    deg    = (int*)take((size_t)n * 4);
    int*    cursor = (int*)take((size_t)n * 4);   // adjacent to deg (joint memset)
    int*    rowptr = (int*)take((size_t)(n + 1) * 4);
    float*  dinv   = (float*)take((size_t)n * 4);
    float*  s      = (float*)take((size_t)n * 4);
    int2*   enorm  = (int2*)take((size_t)e * 8);
    int*    bsum   = (int*)take((size_t)512 * 4);
    __half* h1     = (__half*)take((size_t)n * 128 * 2);
    (void)ws_size;

    int egrid = (e + 255) / 256; if (egrid > 2048) egrid = 2048;
    int ngrid = (n + 255) / 256;
    int nscan = (n + 511) / 512;   // 98 blocks (must be <= 512)

    hipMemsetAsync(deg, 0, (((size_t)n * 4 + 255) & ~(size_t)255) + (size_t)n * 4, stream);

    hipLaunchKernelGGL(k_count_deg, dim3(egrid), dim3(256), 0, stream, dstp, deg, e);
    hipLaunchKernelGGL(k_scan1, dim3(nscan), dim3(512), 0, stream, deg, dinv, bsum, n);
    hipLaunchKernelGGL(k_scan3, dim3(nscan), dim3(512), 0, stream, deg, bsum, rowptr, n);
    hipLaunchKernelGGL(k_scatter, dim3(egrid), dim3(256), 0, stream,
                       srcp, dstp, rowptr, cursor, dinv, enorm, e);
    hipLaunchKernelGGL(k_gemm1, dim3((n + GR - 1) / GR), dim3(512), 0, stream,
                       x, W1, h1, n);
    hipLaunchKernelGGL(k_agg_s, dim3(2048), dim3(256), 0, stream,
                       rowptr, enorm, dinv, h1, b1, W2, s, n);
    hipLaunchKernelGGL(k_out2, dim3(ngrid), dim3(256), 0, stream,
                       rowptr, enorm, dinv, s, b2, out, n);
}

// Round 12
// 218.768 us; speedup vs baseline: 1.3314x; 1.0972x over previous
//
#include <hip/hip_runtime.h>
#include <hip/hip_fp16.h>

using f16x8 = __attribute__((ext_vector_type(8))) _Float16;
using f32x4 = __attribute__((ext_vector_type(4))) float;

// ---------------- CSR build ----------------

__global__ void k_count_deg(const int* __restrict__ dst, int* __restrict__ deg, int e) {
    int i = blockIdx.x * blockDim.x + threadIdx.x;
    int stride = gridDim.x * blockDim.x;
    for (; i < e; i += stride) atomicAdd(&deg[dst[i]], 1);
}

// pass 1: per-block (512 elems) sums + dinv = rsqrt(deg+1)
__global__ __launch_bounds__(512) void k_scan1(const int* __restrict__ deg,
                                               float* __restrict__ dinv,
                                               int* __restrict__ bsum, int n) {
    int t = threadIdx.x;
    int i = blockIdx.x * 512 + t;
    int d = (i < n) ? deg[i] : 0;
    if (i < n) dinv[i] = rsqrtf((float)(d + 1));   // +1 self-loop
    int v = d;
#pragma unroll
    for (int off = 32; off > 0; off >>= 1) v += __shfl_xor(v, off, 64);
    __shared__ int wsum[8];
    if ((t & 63) == 0) wsum[t >> 6] = v;
    __syncthreads();
    if (t == 0) {
        int s = 0;
#pragma unroll
        for (int j = 0; j < 8; ++j) s += wsum[j];
        bsum[blockIdx.x] = s;
    }
}

// pass 2 (merged): block offset from bsum in-block, then local scan -> rowptr
__global__ __launch_bounds__(512) void k_scan3(const int* __restrict__ deg,
                                               const int* __restrict__ bsum,
                                               int* __restrict__ rowptr, int n) {
    __shared__ int sm[512];
    __shared__ int sboff;
    int t = threadIdx.x;
    int v = (t < blockIdx.x) ? bsum[t] : 0;
#pragma unroll
    for (int off = 32; off > 0; off >>= 1) v += __shfl_xor(v, off, 64);
    if ((t & 63) == 0) sm[t >> 6] = v;
    __syncthreads();
    if (t == 0) {
        int s = 0;
#pragma unroll
        for (int j = 0; j < 8; ++j) s += sm[j];
        sboff = s;
    }
    __syncthreads();
    int boff = sboff;
    __syncthreads();                     // sm reuse barrier
    int i = blockIdx.x * 512 + t;
    int d = (i < n) ? deg[i] : 0;
    sm[t] = d;
    __syncthreads();
    for (int dd = 1; dd < 512; dd <<= 1) {
        int vv = (t >= dd) ? sm[t - dd] : 0;
        __syncthreads();
        sm[t] += vv;
        __syncthreads();
    }
    int excl = sm[t] - d;
    if (i < n) {
        rowptr[i] = boff + excl;
        if (i == n - 1) rowptr[n] = boff + excl + d;
    }
}

// scatter-fill packed edge records {src, norm=dinv[src]*dinv[dst]}
__global__ void k_scatter(const int* __restrict__ src, const int* __restrict__ dst,
                          const int* __restrict__ rowptr, int* __restrict__ cursor,
                          const float* __restrict__ dinv,
                          int2* __restrict__ enorm, int e) {
    int i = blockIdx.x * blockDim.x + threadIdx.x;
    int stride = gridDim.x * blockDim.x;
    for (; i < e; i += stride) {
        int ss = src[i];
        int dd = dst[i];
        int pos = rowptr[dd] + atomicAdd(&cursor[dd], 1);
        float nn = dinv[ss] * dinv[dd];
        enorm[pos] = make_int2(ss, __float_as_int(nn));
    }
}

// ---------------- layer 1 GEMM via MFMA: h1 (fp16) = x @ W1 ----------------
// 256 threads = 4 waves x 16 rows; W1 fp16 in LDS pre-swizzled into B-frag order.
// mfma_f32_16x16x32_f16 layouts (CDNA4): A[m][k]: m=l&15, k=(l>>4)*8+i;
// B[k][n]: n=l&15, k=(l>>4)*8+i; D[m][n]: m=(l>>4)*4+r, n=l&15.

__global__ __launch_bounds__(256) void k_gemm1(const float* __restrict__ x,
                                               const float* __restrict__ W,
                                               __half* __restrict__ h1, int n) {
    // Wf[nt][kc][lane][i] : nt=n>>4 (8), kc=k>>5 (4), lane=((k>>3)&3)*16+(n&15), i=k&7
    __shared__ _Float16 Wf[8 * 4 * 64 * 8];   // 16384 halves = 32 KB
    int t = threadIdx.x;

    // stage + convert + swizzle W (float4 loads, 16/thread, coalesced)
    const float4* Wg4 = (const float4*)W;
#pragma unroll
    for (int ii = 0; ii < 16; ++ii) {
        int idx4 = t + 256 * ii;            // float4 index 0..4095
        int k  = idx4 >> 5;                 // 0..127
        int n0 = (idx4 & 31) * 4;           // 0..124
        float4 w = Wg4[idx4];
        int nt = n0 >> 4;
        int kc = k >> 5;
        int ln = ((k >> 3) & 3) * 16 + (n0 & 15);
        int i  = k & 7;
        int base = (((nt << 2) + kc) * 64 + ln) * 8 + i;
        Wf[base]      = (_Float16)w.x;
        Wf[base + 8]  = (_Float16)w.y;
        Wf[base + 16] = (_Float16)w.z;
        Wf[base + 24] = (_Float16)w.w;
    }
    __syncthreads();

    int lane = t & 63;
    int w_id = t >> 6;                      // wave 0..3
    int row0 = blockIdx.x * 64 + w_id * 16; // 16 rows per wave
    int arow = row0 + (lane & 15);
    if (arow >= n) arow = n - 1;            // clamped read; stores guarded
    int kb = (lane >> 4) * 8;               // k-base within 32-chunk

    f32x4 acc[8];
#pragma unroll
    for (int nt = 0; nt < 8; ++nt) acc[nt] = (f32x4){0.f, 0.f, 0.f, 0.f};

    const float* xr = x + (size_t)arow * 128;
#pragma unroll
    for (int kc = 0; kc < 4; ++kc) {
        float4 xa = *(const float4*)(xr + kc * 32 + kb);
        float4 xb = *(const float4*)(xr + kc * 32 + kb + 4);
        f16x8 a;
        a[0] = (_Float16)xa.x; a[1] = (_Float16)xa.y;
        a[2] = (_Float16)xa.z; a[3] = (_Float16)xa.w;
        a[4] = (_Float16)xb.x; a[5] = (_Float16)xb.y;
        a[6] = (_Float16)xb.z; a[7] = (_Float16)xb.w;
#pragma unroll
        for (int nt = 0; nt < 8; ++nt) {
            f16x8 b = *(const f16x8*)&Wf[(((nt << 2) + kc) * 64 + lane) * 8];
            acc[nt] = __builtin_amdgcn_mfma_f32_16x16x32_f16(a, b, acc[nt], 0, 0, 0);
        }
    }

    int drow = row0 + (lane >> 4) * 4;      // D rows drow..drow+3, col = lane&15
#pragma unroll
    for (int r = 0; r < 4; ++r) {
        int grow = drow + r;
        if (grow < n) {
#pragma unroll
            for (int nt = 0; nt < 8; ++nt)
                h1[(size_t)grow * 128 + nt * 16 + (lane & 15)] =
                    __float2half(acc[nt][r]);
        }
    }
}

// ---------------- fused layer-1 agg + bias + relu + W2 dot ----------------
// one wave per node; lane covers cols 2l,2l+1 (half2 = 4B gather per lane).

__global__ __launch_bounds__(256) void k_agg_s(
    const int* __restrict__ rowptr, const int2* __restrict__ enorm,
    const float* __restrict__ dinv, const __half* __restrict__ h1,
    const float* __restrict__ b1, const float* __restrict__ W2,
    float* __restrict__ s, int n) {
    int lane = threadIdx.x & 63;
    int wid = blockIdx.x * (blockDim.x >> 6) + (threadIdx.x >> 6);
    wid = __builtin_amdgcn_readfirstlane(wid);
    int nw = gridDim.x * (blockDim.x >> 6);
    float2 bb = ((const float2*)b1)[lane];
    float2 ww = ((const float2*)W2)[lane];
    for (int i = wid; i < n; i += nw) {
        float di = dinv[i];
        float2 acc = __half22float2(((const __half2*)(h1 + (size_t)i * 128))[lane]);
        float self = di * di;
        acc.x *= self; acc.y *= self;
        int j = rowptr[i], end = rowptr[i + 1];
        for (; j + 4 <= end; j += 4) {
            int2 e0 = enorm[j],     e1 = enorm[j + 1];
            int2 e2 = enorm[j + 2], e3 = enorm[j + 3];
            float n0 = __int_as_float(e0.y), n1 = __int_as_float(e1.y);
            float n2 = __int_as_float(e2.y), n3 = __int_as_float(e3.y);
            float2 v0 = __half22float2(((const __half2*)(h1 + (size_t)e0.x * 128))[lane]);
            float2 v1 = __half22float2(((const __half2*)(h1 + (size_t)e1.x * 128))[lane]);
            float2 v2 = __half22float2(((const __half2*)(h1 + (size_t)e2.x * 128))[lane]);
            float2 v3 = __half22float2(((const __half2*)(h1 + (size_t)e3.x * 128))[lane]);
            acc.x += v0.x * n0; acc.y += v0.y * n0;
            acc.x += v1.x * n1; acc.y += v1.y * n1;
            acc.x += v2.x * n2; acc.y += v2.y * n2;
            acc.x += v3.x * n3; acc.y += v3.y * n3;
        }
        for (; j < end; ++j) {
            int2 e0 = enorm[j];
            float nn = __int_as_float(e0.y);
            float2 v = __half22float2(((const __half2*)(h1 + (size_t)e0.x * 128))[lane]);
            acc.x += v.x * nn; acc.y += v.y * nn;
        }
        float p = fmaxf(acc.x + bb.x, 0.f) * ww.x + fmaxf(acc.y + bb.y, 0.f) * ww.y;
#pragma unroll
        for (int off = 32; off > 0; off >>= 1)
            p += __shfl_xor(p, off, 64);
        if (lane == 0) s[i] = p;
    }
}

// ---------------- layer 2: per-thread CSR gather of s via packed records ----------------

__global__ void k_out2(const int* __restrict__ rowptr, const int2* __restrict__ enorm,
                       const float* __restrict__ dinv, const float* __restrict__ s,
                       const float* __restrict__ b2, float* __restrict__ out, int n) {
    int i = blockIdx.x * blockDim.x + threadIdx.x;
    if (i >= n) return;
    float di = dinv[i];
    float acc = di * di * s[i];            // self-loop
    int j = rowptr[i], end = rowptr[i + 1];
    for (; j < end; ++j) {
        int2 e0 = enorm[j];
        acc += __int_as_float(e0.y) * s[e0.x];
    }
    out[i] = b2[0] + acc;
}

// ---------------- launch ----------------

extern "C" void kernel_launch(void* const* d_in, const int* in_sizes, int n_in,
                              void* d_out, int out_size, void* d_ws, size_t ws_size,
                              hipStream_t stream) {
    const float* x  = (const float*)d_in[0];
    const int*   ei = (const int*)d_in[1];   // [2,E] int32
    const float* W1 = (const float*)d_in[2];
    const float* b1 = (const float*)d_in[3];
    const float* W2 = (const float*)d_in[4];
    const float* b2 = (const float*)d_in[5];
    float* out = (float*)d_out;

    int n = in_sizes[0] / 128;
    int e = in_sizes[1] / 2;
    const int* srcp = ei;
    const int* dstp = ei + e;

    char* ws = (char*)d_ws;
    size_t off = 0;
    auto take = [&](size_t bytes) -> char* {
        char* p = ws + off;
        off += (bytes + 255) & ~(size_t)255;
        return p;
    };
    int*    deg    = (int*)take((size_t)n * 4);
    int*    cursor = (int*)take((size_t)n * 4);   // adjacent to deg (joint memset)
    int*    rowptr = (int*)take((size_t)(n + 1) * 4);
    float*  dinv   = (float*)take((size_t)n * 4);
    float*  s      = (float*)take((size_t)n * 4);
    int2*   enorm  = (int2*)take((size_t)e * 8);
    int*    bsum   = (int*)take((size_t)512 * 4);
    __half* h1     = (__half*)take((size_t)n * 128 * 2);
    (void)ws_size;

    int egrid = (e + 255) / 256; if (egrid > 2048) egrid = 2048;
    int ngrid = (n + 255) / 256;
    int nscan = (n + 511) / 512;   // 98 blocks (must be <= 512)

    hipMemsetAsync(deg, 0, (((size_t)n * 4 + 255) & ~(size_t)255) + (size_t)n * 4, stream);

    hipLaunchKernelGGL(k_count_deg, dim3(egrid), dim3(256), 0, stream, dstp, deg, e);
    hipLaunchKernelGGL(k_scan1, dim3(nscan), dim3(512), 0, stream, deg, dinv, bsum, n);
    hipLaunchKernelGGL(k_scan3, dim3(nscan), dim3(512), 0, stream, deg, bsum, rowptr, n);
    hipLaunchKernelGGL(k_scatter, dim3(egrid), dim3(256), 0, stream,
                       srcp, dstp, rowptr, cursor, dinv, enorm, e);
    hipLaunchKernelGGL(k_gemm1, dim3((n + 63) / 64), dim3(256), 0, stream,
                       x, W1, h1, n);
    hipLaunchKernelGGL(k_agg_s, dim3(2048), dim3(256), 0, stream,
                       rowptr, enorm, dinv, h1, b1, W2, s, n);
    hipLaunchKernelGGL(k_out2, dim3(ngrid), dim3(256), 0, stream,
                       rowptr, enorm, dinv, s, b2, out, n);
}

// Round 13
// 190.656 us; speedup vs baseline: 1.5277x; 1.1475x over previous
//
#include <hip/hip_runtime.h>
#include <hip/hip_fp16.h>

using f16x8 = __attribute__((ext_vector_type(8))) _Float16;
using f32x4 = __attribute__((ext_vector_type(4))) float;

// ---------------- CSR build ----------------

// count pass also records each edge's slot within its dst row
__global__ void k_count_pos(const int* __restrict__ dst, int* __restrict__ deg,
                            int* __restrict__ pos, int e) {
    int i = blockIdx.x * blockDim.x + threadIdx.x;
    int stride = gridDim.x * blockDim.x;
    for (; i < e; i += stride) pos[i] = atomicAdd(&deg[dst[i]], 1);
}

// pass 1: per-block (512 elems) sums + dinv = rsqrt(deg+1)
__global__ __launch_bounds__(512) void k_scan1(const int* __restrict__ deg,
                                               float* __restrict__ dinv,
                                               int* __restrict__ bsum, int n) {
    int t = threadIdx.x;
    int i = blockIdx.x * 512 + t;
    int d = (i < n) ? deg[i] : 0;
    if (i < n) dinv[i] = rsqrtf((float)(d + 1));   // +1 self-loop
    int v = d;
#pragma unroll
    for (int off = 32; off > 0; off >>= 1) v += __shfl_xor(v, off, 64);
    __shared__ int wsum[8];
    if ((t & 63) == 0) wsum[t >> 6] = v;
    __syncthreads();
    if (t == 0) {
        int s = 0;
#pragma unroll
        for (int j = 0; j < 8; ++j) s += wsum[j];
        bsum[blockIdx.x] = s;
    }
}

// pass 2 (merged): block offset from bsum in-block, then local scan -> rowptr
__global__ __launch_bounds__(512) void k_scan3(const int* __restrict__ deg,
                                               const int* __restrict__ bsum,
                                               int* __restrict__ rowptr, int n) {
    __shared__ int sm[512];
    __shared__ int sboff;
    int t = threadIdx.x;
    int v = (t < blockIdx.x) ? bsum[t] : 0;
#pragma unroll
    for (int off = 32; off > 0; off >>= 1) v += __shfl_xor(v, off, 64);
    if ((t & 63) == 0) sm[t >> 6] = v;
    __syncthreads();
    if (t == 0) {
        int s = 0;
#pragma unroll
        for (int j = 0; j < 8; ++j) s += sm[j];
        sboff = s;
    }
    __syncthreads();
    int boff = sboff;
    __syncthreads();                     // sm reuse barrier
    int i = blockIdx.x * 512 + t;
    int d = (i < n) ? deg[i] : 0;
    sm[t] = d;
    __syncthreads();
    for (int dd = 1; dd < 512; dd <<= 1) {
        int vv = (t >= dd) ? sm[t - dd] : 0;
        __syncthreads();
        sm[t] += vv;
        __syncthreads();
    }
    int excl = sm[t] - d;
    if (i < n) {
        rowptr[i] = boff + excl;
        if (i == n - 1) rowptr[n] = boff + excl + d;
    }
}

// atomic-free fill of packed edge records {src, norm=dinv[src]*dinv[dst]}
__global__ void k_fill(const int* __restrict__ src, const int* __restrict__ dst,
                       const int* __restrict__ pos, const int* __restrict__ rowptr,
                       const float* __restrict__ dinv,
                       int2* __restrict__ enorm, int e) {
    int i = blockIdx.x * blockDim.x + threadIdx.x;
    int stride = gridDim.x * blockDim.x;
    for (; i < e; i += stride) {
        int ss = src[i];
        int dd = dst[i];
        float nn = dinv[ss] * dinv[dd];
        enorm[rowptr[dd] + pos[i]] = make_int2(ss, __float_as_int(nn));
    }
}

// ---------------- layer 1 GEMM via MFMA: h1 (fp16) = x @ W1 ----------------
// 256 threads = 4 waves x 16 rows; W1 fp16 in LDS pre-swizzled into B-frag order.

__global__ __launch_bounds__(256) void k_gemm1(const float* __restrict__ x,
                                               const float* __restrict__ W,
                                               __half* __restrict__ h1, int n) {
    __shared__ _Float16 Wf[8 * 4 * 64 * 8];   // 32 KB
    int t = threadIdx.x;

    const float4* Wg4 = (const float4*)W;
#pragma unroll
    for (int ii = 0; ii < 16; ++ii) {
        int idx4 = t + 256 * ii;            // float4 index 0..4095
        int k  = idx4 >> 5;                 // 0..127
        int n0 = (idx4 & 31) * 4;           // 0..124
        float4 w = Wg4[idx4];
        int nt = n0 >> 4;
        int kc = k >> 5;
        int ln = ((k >> 3) & 3) * 16 + (n0 & 15);
        int i  = k & 7;
        int base = (((nt << 2) + kc) * 64 + ln) * 8 + i;
        Wf[base]      = (_Float16)w.x;
        Wf[base + 8]  = (_Float16)w.y;
        Wf[base + 16] = (_Float16)w.z;
        Wf[base + 24] = (_Float16)w.w;
    }
    __syncthreads();

    int lane = t & 63;
    int w_id = t >> 6;
    int row0 = blockIdx.x * 64 + w_id * 16;
    int arow = row0 + (lane & 15);
    if (arow >= n) arow = n - 1;
    int kb = (lane >> 4) * 8;

    f32x4 acc[8];
#pragma unroll
    for (int nt = 0; nt < 8; ++nt) acc[nt] = (f32x4){0.f, 0.f, 0.f, 0.f};

    const float* xr = x + (size_t)arow * 128;
#pragma unroll
    for (int kc = 0; kc < 4; ++kc) {
        float4 xa = *(const float4*)(xr + kc * 32 + kb);
        float4 xb = *(const float4*)(xr + kc * 32 + kb + 4);
        f16x8 a;
        a[0] = (_Float16)xa.x; a[1] = (_Float16)xa.y;
        a[2] = (_Float16)xa.z; a[3] = (_Float16)xa.w;
        a[4] = (_Float16)xb.x; a[5] = (_Float16)xb.y;
        a[6] = (_Float16)xb.z; a[7] = (_Float16)xb.w;
#pragma unroll
        for (int nt = 0; nt < 8; ++nt) {
            f16x8 b = *(const f16x8*)&Wf[(((nt << 2) + kc) * 64 + lane) * 8];
            acc[nt] = __builtin_amdgcn_mfma_f32_16x16x32_f16(a, b, acc[nt], 0, 0, 0);
        }
    }

    int drow = row0 + (lane >> 4) * 4;
#pragma unroll
    for (int r = 0; r < 4; ++r) {
        int grow = drow + r;
        if (grow < n) {
#pragma unroll
            for (int nt = 0; nt < 8; ++nt)
                h1[(size_t)grow * 128 + nt * 16 + (lane & 15)] =
                    __float2half(acc[nt][r]);
        }
    }
}

// ---------------- fused layer-1 agg + bias + relu + W2 dot ----------------
// one wave per node; lane covers cols 2l,2l+1; edge loop unrolled x8 for MLP.

__global__ __launch_bounds__(256) void k_agg_s(
    const int* __restrict__ rowptr, const int2* __restrict__ enorm,
    const float* __restrict__ dinv, const __half* __restrict__ h1,
    const float* __restrict__ b1, const float* __restrict__ W2,
    float* __restrict__ s, int n) {
    int lane = threadIdx.x & 63;
    int wid = blockIdx.x * (blockDim.x >> 6) + (threadIdx.x >> 6);
    wid = __builtin_amdgcn_readfirstlane(wid);
    int nw = gridDim.x * (blockDim.x >> 6);
    float2 bb = ((const float2*)b1)[lane];
    float2 ww = ((const float2*)W2)[lane];
    for (int i = wid; i < n; i += nw) {
        float di = dinv[i];
        float2 acc = __half22float2(((const __half2*)(h1 + (size_t)i * 128))[lane]);
        float self = di * di;
        acc.x *= self; acc.y *= self;
        int j = rowptr[i], end = rowptr[i + 1];
        for (; j + 8 <= end; j += 8) {
            int2 er[8];
#pragma unroll
            for (int q = 0; q < 8; ++q) er[q] = enorm[j + q];
            __half2 vh[8];
#pragma unroll
            for (int q = 0; q < 8; ++q)
                vh[q] = ((const __half2*)(h1 + (size_t)er[q].x * 128))[lane];
#pragma unroll
            for (int q = 0; q < 8; ++q) {
                float nn = __int_as_float(er[q].y);
                float2 v = __half22float2(vh[q]);
                acc.x += v.x * nn; acc.y += v.y * nn;
            }
        }
        for (; j < end; ++j) {
            int2 e0 = enorm[j];
            float nn = __int_as_float(e0.y);
            float2 v = __half22float2(((const __half2*)(h1 + (size_t)e0.x * 128))[lane]);
            acc.x += v.x * nn; acc.y += v.y * nn;
        }
        float p = fmaxf(acc.x + bb.x, 0.f) * ww.x + fmaxf(acc.y + bb.y, 0.f) * ww.y;
#pragma unroll
        for (int off = 32; off > 0; off >>= 1)
            p += __shfl_xor(p, off, 64);
        if (lane == 0) s[i] = p;
    }
}

// ---------------- layer 2: per-thread CSR gather of s, unrolled x4 ----------------

__global__ void k_out2(const int* __restrict__ rowptr, const int2* __restrict__ enorm,
                       const float* __restrict__ dinv, const float* __restrict__ s,
                       const float* __restrict__ b2, float* __restrict__ out, int n) {
    int i = blockIdx.x * blockDim.x + threadIdx.x;
    if (i >= n) return;
    float di = dinv[i];
    float acc = di * di * s[i];            // self-loop
    int j = rowptr[i], end = rowptr[i + 1];
    float a0 = 0.f, a1 = 0.f, a2 = 0.f, a3 = 0.f;
    for (; j + 4 <= end; j += 4) {
        int2 e0 = enorm[j],     e1 = enorm[j + 1];
        int2 e2 = enorm[j + 2], e3 = enorm[j + 3];
        float s0 = s[e0.x], s1 = s[e1.x], s2 = s[e2.x], s3 = s[e3.x];
        a0 += __int_as_float(e0.y) * s0;
        a1 += __int_as_float(e1.y) * s1;
        a2 += __int_as_float(e2.y) * s2;
        a3 += __int_as_float(e3.y) * s3;
    }
    acc += (a0 + a1) + (a2 + a3);
    for (; j < end; ++j) {
        int2 e0 = enorm[j];
        acc += __int_as_float(e0.y) * s[e0.x];
    }
    out[i] = b2[0] + acc;
}

// ---------------- launch ----------------

extern "C" void kernel_launch(void* const* d_in, const int* in_sizes, int n_in,
                              void* d_out, int out_size, void* d_ws, size_t ws_size,
                              hipStream_t stream) {
    const float* x  = (const float*)d_in[0];
    const int*   ei = (const int*)d_in[1];   // [2,E] int32
    const float* W1 = (const float*)d_in[2];
    const float* b1 = (const float*)d_in[3];
    const float* W2 = (const float*)d_in[4];
    const float* b2 = (const float*)d_in[5];
    float* out = (float*)d_out;

    int n = in_sizes[0] / 128;
    int e = in_sizes[1] / 2;
    const int* srcp = ei;
    const int* dstp = ei + e;

    char* ws = (char*)d_ws;
    size_t off = 0;
    auto take = [&](size_t bytes) -> char* {
        char* p = ws + off;
        off += (bytes + 255) & ~(size_t)255;
        return p;
    };
    int*    deg    = (int*)take((size_t)n * 4);
    int*    rowptr = (int*)take((size_t)(n + 1) * 4);
    float*  dinv   = (float*)take((size_t)n * 4);
    float*  s      = (float*)take((size_t)n * 4);
    int*    pos    = (int*)take((size_t)e * 4);
    int2*   enorm  = (int2*)take((size_t)e * 8);
    int*    bsum   = (int*)take((size_t)512 * 4);
    __half* h1     = (__half*)take((size_t)n * 128 * 2);
    (void)ws_size;

    int egrid = (e + 255) / 256; if (egrid > 2048) egrid = 2048;
    int ngrid = (n + 255) / 256;
    int nscan = (n + 511) / 512;   // 98 blocks (must be <= 512)

    hipMemsetAsync(deg, 0, (size_t)n * 4, stream);

    hipLaunchKernelGGL(k_count_pos, dim3(egrid), dim3(256), 0, stream,
                       dstp, deg, pos, e);
    hipLaunchKernelGGL(k_scan1, dim3(nscan), dim3(512), 0, stream, deg, dinv, bsum, n);
    hipLaunchKernelGGL(k_scan3, dim3(nscan), dim3(512), 0, stream, deg, bsum, rowptr, n);
    hipLaunchKernelGGL(k_fill, dim3(egrid), dim3(256), 0, stream,
                       srcp, dstp, pos, rowptr, dinv, enorm, e);
    hipLaunchKernelGGL(k_gemm1, dim3((n + 63) / 64), dim3(256), 0, stream,
                       x, W1, h1, n);
    hipLaunchKernelGGL(k_agg_s, dim3(2048), dim3(256), 0, stream,
                       rowptr, enorm, dinv, h1, b1, W2, s, n);
    hipLaunchKernelGGL(k_out2, dim3(ngrid), dim3(256), 0, stream,
                       rowptr, enorm, dinv, s, b2, out, n);
}

// Round 14
// 175.779 us; speedup vs baseline: 1.6570x; 1.0846x over previous
//
#include <hip/hip_runtime.h>
#include <hip/hip_fp16.h>

using f16x8 = __attribute__((ext_vector_type(8))) _Float16;
using f32x4 = __attribute__((ext_vector_type(4))) float;

// ---------------- fused: layer-1 MFMA GEMM  ||  degree count+pos ----------------
// blocks [0, gemmBlocks): h1(fp16) = x @ W1 via mfma_f32_16x16x32_f16
// blocks [gemmBlocks, gridDim): pos[i] = atomicAdd(&deg[dst[i]], 1)
// The two phases are data-independent; fusing overlaps MFMA compute with
// atomic latency and removes one serialized dispatch.

__global__ __launch_bounds__(256) void k_gemm_count(
    const float* __restrict__ x, const float* __restrict__ W,
    __half* __restrict__ h1, int n,
    const int* __restrict__ dst, int* __restrict__ deg,
    int* __restrict__ pos, int e, int gemmBlocks) {
    __shared__ _Float16 Wf[8 * 4 * 64 * 8];   // 32 KB (gemm path only)
    int t = threadIdx.x;

    if ((int)blockIdx.x >= gemmBlocks) {
        // ---- count path ----
        int cb = blockIdx.x - gemmBlocks;
        int i = cb * 256 + t;
        int stride = (gridDim.x - gemmBlocks) * 256;
        for (; i < e; i += stride) pos[i] = atomicAdd(&deg[dst[i]], 1);
        return;
    }

    // ---- gemm path ----
    const float4* Wg4 = (const float4*)W;
#pragma unroll
    for (int ii = 0; ii < 16; ++ii) {
        int idx4 = t + 256 * ii;            // float4 index 0..4095
        int k  = idx4 >> 5;                 // 0..127
        int n0 = (idx4 & 31) * 4;           // 0..124
        float4 w = Wg4[idx4];
        int nt = n0 >> 4;
        int kc = k >> 5;
        int ln = ((k >> 3) & 3) * 16 + (n0 & 15);
        int i  = k & 7;
        int base = (((nt << 2) + kc) * 64 + ln) * 8 + i;
        Wf[base]      = (_Float16)w.x;
        Wf[base + 8]  = (_Float16)w.y;
        Wf[base + 16] = (_Float16)w.z;
        Wf[base + 24] = (_Float16)w.w;
    }
    __syncthreads();

    int lane = t & 63;
    int w_id = t >> 6;
    int row0 = blockIdx.x * 64 + w_id * 16;
    int arow = row0 + (lane & 15);
    if (arow >= n) arow = n - 1;
    int kb = (lane >> 4) * 8;

    f32x4 acc[8];
#pragma unroll
    for (int nt = 0; nt < 8; ++nt) acc[nt] = (f32x4){0.f, 0.f, 0.f, 0.f};

    const float* xr = x + (size_t)arow * 128;
#pragma unroll
    for (int kc = 0; kc < 4; ++kc) {
        float4 xa = *(const float4*)(xr + kc * 32 + kb);
        float4 xb = *(const float4*)(xr + kc * 32 + kb + 4);
        f16x8 a;
        a[0] = (_Float16)xa.x; a[1] = (_Float16)xa.y;
        a[2] = (_Float16)xa.z; a[3] = (_Float16)xa.w;
        a[4] = (_Float16)xb.x; a[5] = (_Float16)xb.y;
        a[6] = (_Float16)xb.z; a[7] = (_Float16)xb.w;
#pragma unroll
        for (int nt = 0; nt < 8; ++nt) {
            f16x8 b = *(const f16x8*)&Wf[(((nt << 2) + kc) * 64 + lane) * 8];
            acc[nt] = __builtin_amdgcn_mfma_f32_16x16x32_f16(a, b, acc[nt], 0, 0, 0);
        }
    }

    int drow = row0 + (lane >> 4) * 4;
#pragma unroll
    for (int r = 0; r < 4; ++r) {
        int grow = drow + r;
        if (grow < n) {
#pragma unroll
            for (int nt = 0; nt < 8; ++nt)
                h1[(size_t)grow * 128 + nt * 16 + (lane & 15)] =
                    __float2half(acc[nt][r]);
        }
    }
}

// pass 1: per-block (512 elems) sums + dinv = rsqrt(deg+1)
__global__ __launch_bounds__(512) void k_scan1(const int* __restrict__ deg,
                                               float* __restrict__ dinv,
                                               int* __restrict__ bsum, int n) {
    int t = threadIdx.x;
    int i = blockIdx.x * 512 + t;
    int d = (i < n) ? deg[i] : 0;
    if (i < n) dinv[i] = rsqrtf((float)(d + 1));   // +1 self-loop
    int v = d;
#pragma unroll
    for (int off = 32; off > 0; off >>= 1) v += __shfl_xor(v, off, 64);
    __shared__ int wsum[8];
    if ((t & 63) == 0) wsum[t >> 6] = v;
    __syncthreads();
    if (t == 0) {
        int s = 0;
#pragma unroll
        for (int j = 0; j < 8; ++j) s += wsum[j];
        bsum[blockIdx.x] = s;
    }
}

// pass 2 (merged): block offset from bsum in-block, then local scan -> rowptr
__global__ __launch_bounds__(512) void k_scan3(const int* __restrict__ deg,
                                               const int* __restrict__ bsum,
                                               int* __restrict__ rowptr, int n) {
    __shared__ int sm[512];
    __shared__ int sboff;
    int t = threadIdx.x;
    int v = (t < blockIdx.x) ? bsum[t] : 0;
#pragma unroll
    for (int off = 32; off > 0; off >>= 1) v += __shfl_xor(v, off, 64);
    if ((t & 63) == 0) sm[t >> 6] = v;
    __syncthreads();
    if (t == 0) {
        int s = 0;
#pragma unroll
        for (int j = 0; j < 8; ++j) s += sm[j];
        sboff = s;
    }
    __syncthreads();
    int boff = sboff;
    __syncthreads();                     // sm reuse barrier
    int i = blockIdx.x * 512 + t;
    int d = (i < n) ? deg[i] : 0;
    sm[t] = d;
    __syncthreads();
    for (int dd = 1; dd < 512; dd <<= 1) {
        int vv = (t >= dd) ? sm[t - dd] : 0;
        __syncthreads();
        sm[t] += vv;
        __syncthreads();
    }
    int excl = sm[t] - d;
    if (i < n) {
        rowptr[i] = boff + excl;
        if (i == n - 1) rowptr[n] = boff + excl + d;
    }
}

// atomic-free fill of packed edge records {src, norm=dinv[src]*dinv[dst]}
__global__ void k_fill(const int* __restrict__ src, const int* __restrict__ dst,
                       const int* __restrict__ pos, const int* __restrict__ rowptr,
                       const float* __restrict__ dinv,
                       int2* __restrict__ enorm, int e) {
    int i = blockIdx.x * blockDim.x + threadIdx.x;
    int stride = gridDim.x * blockDim.x;
    for (; i < e; i += stride) {
        int ss = src[i];
        int dd = dst[i];
        float nn = dinv[ss] * dinv[dd];
        enorm[rowptr[dd] + pos[i]] = make_int2(ss, __float_as_int(nn));
    }
}

// ---------------- fused layer-1 agg + bias + relu + W2 dot ----------------
// one wave per node; lane covers cols 2l,2l+1; edge loop unrolled x8 for MLP.

__global__ __launch_bounds__(256) void k_agg_s(
    const int* __restrict__ rowptr, const int2* __restrict__ enorm,
    const float* __restrict__ dinv, const __half* __restrict__ h1,
    const float* __restrict__ b1, const float* __restrict__ W2,
    float* __restrict__ s, int n) {
    int lane = threadIdx.x & 63;
    int wid = blockIdx.x * (blockDim.x >> 6) + (threadIdx.x >> 6);
    wid = __builtin_amdgcn_readfirstlane(wid);
    int nw = gridDim.x * (blockDim.x >> 6);
    float2 bb = ((const float2*)b1)[lane];
    float2 ww = ((const float2*)W2)[lane];
    for (int i = wid; i < n; i += nw) {
        float di = dinv[i];
        float2 acc = __half22float2(((const __half2*)(h1 + (size_t)i * 128))[lane]);
        float self = di * di;
        acc.x *= self; acc.y *= self;
        int j = rowptr[i], end = rowptr[i + 1];
        for (; j + 8 <= end; j += 8) {
            int2 er[8];
#pragma unroll
            for (int q = 0; q < 8; ++q) er[q] = enorm[j + q];
            __half2 vh[8];
#pragma unroll
            for (int q = 0; q < 8; ++q)
                vh[q] = ((const __half2*)(h1 + (size_t)er[q].x * 128))[lane];
#pragma unroll
            for (int q = 0; q < 8; ++q) {
                float nn = __int_as_float(er[q].y);
                float2 v = __half22float2(vh[q]);
                acc.x += v.x * nn; acc.y += v.y * nn;
            }
        }
        for (; j < end; ++j) {
            int2 e0 = enorm[j];
            float nn = __int_as_float(e0.y);
            float2 v = __half22float2(((const __half2*)(h1 + (size_t)e0.x * 128))[lane]);
            acc.x += v.x * nn; acc.y += v.y * nn;
        }
        float p = fmaxf(acc.x + bb.x, 0.f) * ww.x + fmaxf(acc.y + bb.y, 0.f) * ww.y;
#pragma unroll
        for (int off = 32; off > 0; off >>= 1)
            p += __shfl_xor(p, off, 64);
        if (lane == 0) s[i] = p;
    }
}

// ---------------- layer 2: per-thread CSR gather of s, unrolled x4 ----------------

__global__ void k_out2(const int* __restrict__ rowptr, const int2* __restrict__ enorm,
                       const float* __restrict__ dinv, const float* __restrict__ s,
                       const float* __restrict__ b2, float* __restrict__ out, int n) {
    int i = blockIdx.x * blockDim.x + threadIdx.x;
    if (i >= n) return;
    float di = dinv[i];
    float acc = di * di * s[i];            // self-loop
    int j = rowptr[i], end = rowptr[i + 1];
    float a0 = 0.f, a1 = 0.f, a2 = 0.f, a3 = 0.f;
    for (; j + 4 <= end; j += 4) {
        int2 e0 = enorm[j],     e1 = enorm[j + 1];
        int2 e2 = enorm[j + 2], e3 = enorm[j + 3];
        float s0 = s[e0.x], s1 = s[e1.x], s2 = s[e2.x], s3 = s[e3.x];
        a0 += __int_as_float(e0.y) * s0;
        a1 += __int_as_float(e1.y) * s1;
        a2 += __int_as_float(e2.y) * s2;
        a3 += __int_as_float(e3.y) * s3;
    }
    acc += (a0 + a1) + (a2 + a3);
    for (; j < end; ++j) {
        int2 e0 = enorm[j];
        acc += __int_as_float(e0.y) * s[e0.x];
    }
    out[i] = b2[0] + acc;
}

// ---------------- launch ----------------

extern "C" void kernel_launch(void* const* d_in, const int* in_sizes, int n_in,
                              void* d_out, int out_size, void* d_ws, size_t ws_size,
                              hipStream_t stream) {
    const float* x  = (const float*)d_in[0];
    const int*   ei = (const int*)d_in[1];   // [2,E] int32
    const float* W1 = (const float*)d_in[2];
    const float* b1 = (const float*)d_in[3];
    const float* W2 = (const float*)d_in[4];
    const float* b2 = (const float*)d_in[5];
    float* out = (float*)d_out;

    int n = in_sizes[0] / 128;
    int e = in_sizes[1] / 2;
    const int* srcp = ei;
    const int* dstp = ei + e;

    char* ws = (char*)d_ws;
    size_t off = 0;
    auto take = [&](size_t bytes) -> char* {
        char* p = ws + off;
        off += (bytes + 255) & ~(size_t)255;
        return p;
    };
    int*    deg    = (int*)take((size_t)n * 4);
    int*    rowptr = (int*)take((size_t)(n + 1) * 4);
    float*  dinv   = (float*)take((size_t)n * 4);
    float*  s      = (float*)take((size_t)n * 4);
    int*    pos    = (int*)take((size_t)e * 4);
    int2*   enorm  = (int2*)take((size_t)e * 8);
    int*    bsum   = (int*)take((size_t)512 * 4);
    __half* h1     = (__half*)take((size_t)n * 128 * 2);
    (void)ws_size;

    int egrid = (e + 255) / 256; if (egrid > 2048) egrid = 2048;
    int ngrid = (n + 255) / 256;
    int nscan = (n + 511) / 512;   // 98 blocks (must be <= 512)
    int gemmBlocks = (n + 63) / 64;

    hipMemsetAsync(deg, 0, (size_t)n * 4, stream);

    hipLaunchKernelGGL(k_gemm_count, dim3(gemmBlocks + 2048), dim3(256), 0, stream,
                       x, W1, h1, n, dstp, deg, pos, e, gemmBlocks);
    hipLaunchKernelGGL(k_scan1, dim3(nscan), dim3(512), 0, stream, deg, dinv, bsum, n);
    hipLaunchKernelGGL(k_scan3, dim3(nscan), dim3(512), 0, stream, deg, bsum, rowptr, n);
    hipLaunchKernelGGL(k_fill, dim3(egrid), dim3(256), 0, stream,
                       srcp, dstp, pos, rowptr, dinv, enorm, e);
    hipLaunchKernelGGL(k_agg_s, dim3(2048), dim3(256), 0, stream,
                       rowptr, enorm, dinv, h1, b1, W2, s, n);
    hipLaunchKernelGGL(k_out2, dim3(ngrid), dim3(256), 0, stream,
                       rowptr, enorm, dinv, s, b2, out, n);
}